// Round 13
// baseline (373.752 us; speedup 1.0000x reference)
//
#include <hip/hip_runtime.h>

// TemporalTX: T=512, B=16, D=128, H=8, DH=128, P=512, J=1024.
// INPUTS fp32; OUTPUT fp32. Workspace intermediates bf16.
// out = [layer_out (1M) | inputs copy (1M) | layer_out copy (1M)] fp32 elems.

typedef short s16x8 __attribute__((ext_vector_type(8)));
typedef float f32x4 __attribute__((ext_vector_type(4)));

#define MFMA(a, b, c) __builtin_amdgcn_mfma_f32_16x16x32_bf16((a), (b), (c), 0, 0, 0)
#define LDS_FENCE() asm volatile("s_waitcnt lgkmcnt(0)" ::: "memory")

__device__ __forceinline__ unsigned short f2b(float f) {
  unsigned int x = __builtin_bit_cast(unsigned int, f);
  x += 0x7fffu + ((x >> 16) & 1u);   // RNE
  return (unsigned short)(x >> 16);
}
__device__ __forceinline__ float b2f(unsigned short u) {
  unsigned int t = ((unsigned int)u) << 16;
  return __builtin_bit_cast(float, t);
}
__device__ __forceinline__ s16x8 ldg8(const unsigned short* p) {  // bf16 x8
  return *(const s16x8*)p;
}
__device__ __forceinline__ s16x8 ldf8(const float* p) {  // fp32 x8 -> bf16 x8
  float4 u = ((const float4*)p)[0];
  float4 v = ((const float4*)p)[1];
  s16x8 r;
  r[0] = (short)f2b(u.x); r[1] = (short)f2b(u.y);
  r[2] = (short)f2b(u.z); r[3] = (short)f2b(u.w);
  r[4] = (short)f2b(v.x); r[5] = (short)f2b(v.y);
  r[6] = (short)f2b(v.z); r[7] = (short)f2b(v.w);
  return r;
}
// async global->LDS DMA, 16B per lane, LDS dest = uniform base + lane*16
__device__ __forceinline__ void gl2lds(const unsigned short* g, unsigned short* l) {
  __builtin_amdgcn_global_load_lds(
      (const __attribute__((address_space(1))) unsigned int*)(g),
      (__attribute__((address_space(3))) unsigned int*)(l), 16, 0, 0);
}

// ---------------------------------------------------------------------------
// Weight pre-conversion fp32 -> bf16 (wkv, wq, wp, wout). 8 elems/thread.
__global__ __launch_bounds__(256, 2) void k_prep(
    const float* __restrict__ wkv, const float* __restrict__ wq,
    const float* __restrict__ wp, const float* __restrict__ wout,
    unsigned short* __restrict__ wkv_b, unsigned short* __restrict__ wq_b,
    unsigned short* __restrict__ wp_b, unsigned short* __restrict__ wout_b) {
  int id = blockIdx.x * 256 + threadIdx.x;  // 81920 total
  const float* src;
  unsigned short* dst;
  int off;
  if (id < 32768) { src = wkv; dst = wkv_b; off = id; }
  else if (id < 49152) { src = wq; dst = wq_b; off = id - 32768; }
  else if (id < 65536) { src = wp; dst = wp_b; off = id - 49152; }
  else { src = wout; dst = wout_b; off = id - 65536; }
  ((s16x8*)dst)[off] = ldf8(src + off * 8);
}

// ---------------------------------------------------------------------------
// KV projection over xm = cat(mem0, x). Block = (ncgrp of 4, b, 128-j range);
// waves split j; A-fragments loaded once, reused for 4 weight chunks.
__global__ __launch_bounds__(256, 2) void k_gemm_kv(
    const float* __restrict__ x, const float* __restrict__ mem,
    const unsigned short* __restrict__ wkv_b,
    unsigned short* __restrict__ Kk, unsigned short* __restrict__ Vt) {
  __shared__ float tbuf[4][16][128];
  const int lane = threadIdx.x & 63;
  const int w = threadIdx.x >> 6;
  const int ncg = (blockIdx.x & 3) * 4;
  const int b = (blockIdx.x >> 2) & 15;
  const int jb = (blockIdx.x >> 6) * 128 + w * 32;
  const int l15 = lane & 15, l4 = lane >> 4;

  s16x8 A[2][4];
#pragma unroll
  for (int g = 0; g < 2; ++g) {
    int jr = jb + g * 16 + l15;
    const float* arow =
        (jr < 512 ? mem + (jr * 16 + b) * 128 : x + ((jr - 512) * 16 + b) * 128) + l4 * 8;
    A[g][0] = ldf8(arow); A[g][1] = ldf8(arow + 32);
    A[g][2] = ldf8(arow + 64); A[g][3] = ldf8(arow + 96);
  }

  for (int q = 0; q < 4; ++q) {
    const int nc = ncg + q;
    f32x4 acc[2][8] = {};
#pragma unroll
    for (int fc = 0; fc < 8; ++fc) {
      const unsigned short* brow = wkv_b + (nc * 128 + fc * 16 + l15) * 128 + l4 * 8;
      s16x8 b0 = ldg8(brow), b1 = ldg8(brow + 32), b2 = ldg8(brow + 64), b3 = ldg8(brow + 96);
#pragma unroll
      for (int g = 0; g < 2; ++g) {
        acc[g][fc] = MFMA(A[g][0], b0, acc[g][fc]);
        acc[g][fc] = MFMA(A[g][1], b1, acc[g][fc]);
        acc[g][fc] = MFMA(A[g][2], b2, acc[g][fc]);
        acc[g][fc] = MFMA(A[g][3], b3, acc[g][fc]);
      }
    }

    if (nc < 8) {  // K part, h = nc
#pragma unroll
      for (int g = 0; g < 2; ++g)
#pragma unroll
        for (int fc = 0; fc < 8; ++fc)
#pragma unroll
          for (int r = 0; r < 4; ++r) {
            int j = jb + g * 16 + l4 * 4 + r;
            Kk[((b * 8 + nc) * 1024 + j) * 128 + fc * 16 + l15] = f2b(acc[g][fc][r]);
          }
    } else {  // V part, h = nc-8: per-group LDS transpose (per-wave slice)
      const int h = nc - 8;
#pragma unroll
      for (int g = 0; g < 2; ++g) {
        LDS_FENCE();
#pragma unroll
        for (int fc = 0; fc < 8; ++fc)
#pragma unroll
          for (int r = 0; r < 4; ++r) tbuf[w][l4 * 4 + r][fc * 16 + l15] = acc[g][fc][r];
        LDS_FENCE();
#pragma unroll
        for (int half = 0; half < 2; ++half) {
          int dd = half * 64 + lane;
          unsigned int wd[8];
#pragma unroll
          for (int pw = 0; pw < 8; ++pw) {
            unsigned int lo = f2b(tbuf[w][2 * pw][dd]);
            unsigned int hi = f2b(tbuf[w][2 * pw + 1][dd]);
            wd[pw] = lo | (hi << 16);
          }
          unsigned short* dst = Vt + ((b * 8 + h) * 128 + dd) * 1024 + jb + g * 16;
          ((uint4*)dst)[0] = make_uint4(wd[0], wd[1], wd[2], wd[3]);
          ((uint4*)dst)[1] = make_uint4(wd[4], wd[5], wd[6], wd[7]);
        }
      }
    }
  }
}

// ---------------------------------------------------------------------------
// P projection: P[h][c][d] = sum_e pe[c][e] * wp[h*128+d][e], pe analytic.
__global__ __launch_bounds__(256, 2) void k_gemm_p(
    const unsigned short* __restrict__ wp_b, unsigned short* __restrict__ Pp) {
  const int lane = threadIdx.x & 63;
  const int w = threadIdx.x >> 6;
  const int nc = blockIdx.x & 7;
  const int c0 = ((blockIdx.x >> 3) * 4 + w) * 16;
  const int l15 = lane & 15, l4 = lane >> 4;

  const float pos = (float)(1023 - (c0 + l15));
  s16x8 a[4];
#pragma unroll
  for (int ks = 0; ks < 4; ++ks)
#pragma unroll
    for (int jj = 0; jj < 8; ++jj) {
      int e = ks * 32 + l4 * 8 + jj;
      int t = e & 63;
      float ang = pos * exp2f(-0.20762050593046014f * (float)t);  // 10000^(-t/64)
      float val = (e < 64) ? sinf(ang) : cosf(ang);
      a[ks][jj] = (short)f2b(val);
    }

  f32x4 acc[8] = {};
#pragma unroll
  for (int fc = 0; fc < 8; ++fc) {
    const unsigned short* brow = wp_b + (nc * 128 + fc * 16 + l15) * 128 + l4 * 8;
    acc[fc] = MFMA(a[0], ldg8(brow), acc[fc]);
    acc[fc] = MFMA(a[1], ldg8(brow + 32), acc[fc]);
    acc[fc] = MFMA(a[2], ldg8(brow + 64), acc[fc]);
    acc[fc] = MFMA(a[3], ldg8(brow + 96), acc[fc]);
  }
#pragma unroll
  for (int fc = 0; fc < 8; ++fc)
#pragma unroll
    for (int r = 0; r < 4; ++r)
      Pp[(nc * 1024 + c0 + l4 * 4 + r) * 128 + fc * 16 + l15] = f2b(acc[fc][r]);
}

// ---------------------------------------------------------------------------
// Flash attention. K/V: block-cooperative fragment-ordered LDS staging (r12).
// P: direct L2 reads (band rows shared across b -> L2-hot). Position diagonal
// via per-wave bf16 band buffer (stride 84 -> 2-way banks, free) instead of
// shfl gather. LDS ~51.5 KB -> 3 blocks/CU.
__global__ __launch_bounds__(256, 3) void k_flash(
    const float* __restrict__ x, const unsigned short* __restrict__ wq_b,
    const unsigned short* __restrict__ Kk, const unsigned short* __restrict__ Vt,
    const unsigned short* __restrict__ Pp,
    const float* __restrict__ uu, const float* __restrict__ vv,
    unsigned short* __restrict__ OA) {
  __shared__ __align__(16) unsigned short L[26368];  // 51.5 KB
  unsigned short* LK = L;            // 16 frag-tiles x 512 (fc*4+ks)
  unsigned short* LV = L + 8192;     // 16 frag-tiles x 512 (fd*2+ks)
  unsigned short* PB = L + 16384;    // probs: 4 waves x [16][72]  (4608)
  unsigned short* BD = L + 20992;    // band: 4 waves x [16][84]   (5376)

  const int lane = threadIdx.x & 63;
  const int w = threadIdx.x >> 6;
  const int bh = blockIdx.x & 127;
  const int igw = 7 - (blockIdx.x >> 7);  // longest blocks first
  const int iw = igw * 64 + w * 16;
  const int b = bh >> 3, h = bh & 7;
  const int l15 = lane & 15, l4 = lane >> 4;
  const float CSCALE = 0.08838834764831845f * 1.4426950408889634f;  // 1/sqrt(128)*log2e

  const unsigned short* K_b = Kk + bh * (1024 * 128);
  const unsigned short* V_b = Vt + bh * (128 * 1024);
  const unsigned short* P_h = Pp + h * (1024 * 128);

  // ---- fused Q projection (per-wave; PB/BD region used as scratch)
  s16x8 qu[4], qv[4];
  {
    const float* arow = x + ((iw + l15) * 16 + b) * 128 + l4 * 8;
    s16x8 a0 = ldf8(arow), a1 = ldf8(arow + 32), a2 = ldf8(arow + 64), a3 = ldf8(arow + 96);
    f32x4 qd[8] = {};
#pragma unroll
    for (int fc = 0; fc < 8; ++fc) {
      const unsigned short* brow = wq_b + (h * 128 + fc * 16 + l15) * 128 + l4 * 8;
      qd[fc] = MFMA(a0, ldg8(brow), qd[fc]);
      qd[fc] = MFMA(a1, ldg8(brow + 32), qd[fc]);
      qd[fc] = MFMA(a2, ldg8(brow + 64), qd[fc]);
      qd[fc] = MFMA(a3, ldg8(brow + 96), qd[fc]);
    }
    unsigned short* qs = L + 16384 + w * 2176;  // [16][136] scratch per wave
#pragma unroll
    for (int fc = 0; fc < 8; ++fc) {
      float ud = uu[h * 128 + fc * 16 + l15];
#pragma unroll
      for (int r = 0; r < 4; ++r) qs[(l4 * 4 + r) * 136 + fc * 16 + l15] = f2b(qd[fc][r] + ud);
    }
    LDS_FENCE();
#pragma unroll
    for (int ks = 0; ks < 4; ++ks)
      qu[ks] = *(const s16x8*)&qs[l15 * 136 + ks * 32 + l4 * 8];
    LDS_FENCE();
#pragma unroll
    for (int fc = 0; fc < 8; ++fc) {
      float vd = vv[h * 128 + fc * 16 + l15];
#pragma unroll
      for (int r = 0; r < 4; ++r) qs[(l4 * 4 + r) * 136 + fc * 16 + l15] = f2b(qd[fc][r] + vd);
    }
    LDS_FENCE();
#pragma unroll
    for (int ks = 0; ks < 4; ++ks)
      qv[ks] = *(const s16x8*)&qs[l15 * 136 + ks * 32 + l4 * 8];
  }
  __syncthreads();  // scratch free before first DMA / band use

  f32x4 O[8] = {};
  float rs[4] = {0.f, 0.f, 0.f, 0.f};

  const int tmax = igw + 9;  // j0 = t*64 covers j <= igw*64+63+512
  for (int t = 0; t < tmax; ++t) {
    const int j0 = t * 64;
    const int c0w = j0 - iw + 496;  // per-wave band base row (>=0)

    // ---- fragment-ordered cooperative DMA: K (4 instr), V (4 instr)
#pragma unroll
    for (int q = 0; q < 4; ++q)
      gl2lds(K_b + (j0 + w * 16 + l15) * 128 + q * 32 + l4 * 8, LK + (w * 4 + q) * 512);
#pragma unroll
    for (int q = 0; q < 4; ++q) {
      int m = w * 4 + q, fd = m >> 1, ks = m & 1;
      gl2lds(V_b + (fd * 16 + l15) * 1024 + j0 + ks * 32 + l4 * 8, LV + m * 512);
    }
    __syncthreads();  // vmcnt drained at barrier -> K/V staged

    // ---- QK^T from LK (contiguous lane*16 reads)
    f32x4 sc[4];
#pragma unroll
    for (int fc = 0; fc < 4; ++fc) {
      f32x4 t4 = {};
#pragma unroll
      for (int ks = 0; ks < 4; ++ks)
        t4 = MFMA(qu[ks], *(const s16x8*)&LK[(fc * 4 + ks) * 512 + lane * 8], t4);
      sc[fc] = t4;
    }

    // ---- position band: P direct from L2, result straight into band buffer
    unsigned short* bw = BD + w * 1344;  // [16][84]
#pragma unroll
    for (int pc = 0; pc < 5; ++pc) {
      int c = c0w + pc * 16 + l15;
      c = (c > 1023) ? 1023 : c;  // clamped rows feed only masked elements
      const unsigned short* pr = P_h + c * 128 + l4 * 8;
      f32x4 t4 = {};
      t4 = MFMA(qv[0], ldg8(pr), t4);
      t4 = MFMA(qv[1], ldg8(pr + 32), t4);
      t4 = MFMA(qv[2], ldg8(pr + 64), t4);
      t4 = MFMA(qv[3], ldg8(pr + 96), t4);
#pragma unroll
      for (int r = 0; r < 4; ++r) bw[(l4 * 4 + r) * 84 + pc * 16 + l15] = f2b(t4[r]);
    }

    // ---- combine + fixed-shift softmax, stage probs (per-wave buffer)
    unsigned short* pb = PB + w * 1152;
#pragma unroll
    for (int fc = 0; fc < 4; ++fc)
#pragma unroll
      for (int r = 0; r < 4; ++r) {
        int li = l4 * 4 + r;
        int jj = fc * 16 + l15;
        float pv = b2f(bw[li * 84 + (jj - li + 15)]);
        float logit = (sc[fc][r] + pv) * CSCALE - 12.0f;  // fixed shift 2^-12
        if (j0 + jj > iw + li + 512) logit = -72.0f;      // masked
        float p = exp2f(logit);
        rs[r] += p;
        pb[li * 72 + jj] = f2b(p);
      }

    // ---- PV from LV (probs same-wave write->read ordering, r3==r4 verified)
    s16x8 pa0 = *(const s16x8*)&pb[l15 * 72 + l4 * 8];
    s16x8 pa1 = *(const s16x8*)&pb[l15 * 72 + 32 + l4 * 8];
#pragma unroll
    for (int fd = 0; fd < 8; ++fd) {
      O[fd] = MFMA(pa0, *(const s16x8*)&LV[(fd * 2) * 512 + lane * 8], O[fd]);
      O[fd] = MFMA(pa1, *(const s16x8*)&LV[(fd * 2 + 1) * 512 + lane * 8], O[fd]);
    }
    __syncthreads();  // WAR: staged K/V consumed before next DMA
  }

  // one-time row-sum reduction
  float lrow[4];
#pragma unroll
  for (int r = 0; r < 4; ++r) {
    float s = rs[r];
#pragma unroll
    for (int off = 1; off < 16; off <<= 1) s += __shfl_xor(s, off, 64);
    lrow[r] = s;
  }
  // epilogue: O/l -> OA[i][b][h*128+d]
#pragma unroll
  for (int fd = 0; fd < 8; ++fd)
#pragma unroll
    for (int r = 0; r < 4; ++r) {
      int li = l4 * 4 + r;
      float o = O[fd][r] / lrow[r];
      OA[((iw + li) * 16 + b) * 1024 + h * 128 + fd * 16 + l15] = f2b(o);
    }
}

// ---------------------------------------------------------------------------
// Output projection: out[i][b][e] = sum_f OA[i][b][f] * wout[e][f], K=1024.
__global__ __launch_bounds__(256, 2) void k_out(
    const unsigned short* __restrict__ OA, const unsigned short* __restrict__ wout_b,
    const float* __restrict__ x, float* __restrict__ out) {
  const int lane = threadIdx.x & 63;
  const int w = threadIdx.x >> 6;
  const int half = blockIdx.x & 1;
  const int rt = (blockIdx.x >> 1) * 4 + w;
  const int l15 = lane & 15, l4 = lane >> 4;

  f32x4 acc[4] = {};
  const unsigned short* arow = OA + (rt * 16 + l15) * 1024 + l4 * 8;
#pragma unroll 4
  for (int ks = 0; ks < 32; ++ks) {
    s16x8 a = ldg8(arow + ks * 32);
#pragma unroll
    for (int fc = 0; fc < 4; ++fc) {
      const unsigned short* brow =
          wout_b + (half * 64 + fc * 16 + l15) * 1024 + ks * 32 + l4 * 8;
      acc[fc] = MFMA(a, ldg8(brow), acc[fc]);
    }
  }
#pragma unroll
  for (int fc = 0; fc < 4; ++fc)
#pragma unroll
    for (int r = 0; r < 4; ++r) {
      int rg = rt * 16 + l4 * 4 + r;
      int e = half * 64 + fc * 16 + l15;
      float v = acc[fc][r];
      out[rg * 128 + e] = v;
      out[2097152 + rg * 128 + e] = v;
    }
  // copy inputs (fp32) -> out1 (fp32, exact)
  const float4* src = (const float4*)(x + rt * 2048 + half * 1024);
  float4* dst = (float4*)(out + 1048576 + rt * 2048 + half * 1024);
  dst[lane] = src[lane];
  dst[64 + lane] = src[64 + lane];
  dst[128 + lane] = src[128 + lane];
  dst[192 + lane] = src[192 + lane];
}

// ---------------------------------------------------------------------------
extern "C" void kernel_launch(void* const* d_in, const int* in_sizes, int n_in,
                              void* d_out, int out_size, void* d_ws, size_t ws_size,
                              hipStream_t stream) {
  (void)in_sizes; (void)n_in; (void)out_size; (void)ws_size;
  const float* x    = (const float*)d_in[0];  // [512][16][128] fp32
  const float* mem  = (const float*)d_in[1];  // [2][512][16][128] fp32
  const float* wkv  = (const float*)d_in[2];  // [2048][128] fp32
  const float* wq   = (const float*)d_in[3];  // [1024][128] fp32
  const float* wp   = (const float*)d_in[4];  // [1024][128] fp32
  const float* wout = (const float*)d_in[5];  // [128][1024] fp32
  const float* uu   = (const float*)d_in[6];  // [8][128] fp32
  const float* vv   = (const float*)d_in[7];  // [8][128] fp32
  float* out = (float*)d_out;                 // fp32, 3,145,728 elems
  unsigned short* ws = (unsigned short*)d_ws;

  unsigned short* Kk     = ws;             // [16][8][1024][128] 16,777,216
  unsigned short* Vt     = ws + 16777216;  // [16][8][128][1024] 16,777,216
  unsigned short* Pp     = ws + 33554432;  // [8][1024][128]      1,048,576
  unsigned short* OA     = ws + 34603008;  // [512][16][1024]     8,388,608
  unsigned short* wkv_b  = ws + 42991616;  // 262,144
  unsigned short* wq_b   = ws + 43253760;  // 131,072
  unsigned short* wp_b   = ws + 43384832;  // 131,072
  unsigned short* wout_b = ws + 43515904;  // 131,072 -> end 43,646,976 (~83.3 MB)

  k_prep<<<320, 256, 0, stream>>>(wkv, wq, wp, wout, wkv_b, wq_b, wp_b, wout_b);
  k_gemm_kv<<<512, 256, 0, stream>>>(x, mem, wkv_b, Kk, Vt);
  k_gemm_p<<<128, 256, 0, stream>>>(wp_b, Pp);
  k_flash<<<1024, 256, 0, stream>>>(x, wq_b, Kk, Vt, Pp, uu, vv, OA);
  k_out<<<256, 256, 0, stream>>>(OA, wout_b, x, out);
}

// Round 15
// 276.888 us; speedup vs baseline: 1.3498x; 1.3498x over previous
//
#include <hip/hip_runtime.h>

// TemporalTX: T=512, B=16, D=128, H=8, DH=128, P=512, J=1024.
// INPUTS fp32; OUTPUT fp32. Workspace intermediates bf16.
// out = [layer_out (1M) | inputs copy (1M) | layer_out copy (1M)] fp32 elems.

typedef short s16x8 __attribute__((ext_vector_type(8)));
typedef float f32x4 __attribute__((ext_vector_type(4)));

#define MFMA(a, b, c) __builtin_amdgcn_mfma_f32_16x16x32_bf16((a), (b), (c), 0, 0, 0)
#define LDS_FENCE() asm volatile("s_waitcnt lgkmcnt(0)" ::: "memory")

__device__ __forceinline__ unsigned short f2b(float f) {
  unsigned int x = __builtin_bit_cast(unsigned int, f);
  x += 0x7fffu + ((x >> 16) & 1u);   // RNE
  return (unsigned short)(x >> 16);
}
__device__ __forceinline__ s16x8 ldg8(const unsigned short* p) {  // bf16 x8
  return *(const s16x8*)p;
}
__device__ __forceinline__ s16x8 ldf8(const float* p) {  // fp32 x8 -> bf16 x8
  float4 u = ((const float4*)p)[0];
  float4 v = ((const float4*)p)[1];
  s16x8 r;
  r[0] = (short)f2b(u.x); r[1] = (short)f2b(u.y);
  r[2] = (short)f2b(u.z); r[3] = (short)f2b(u.w);
  r[4] = (short)f2b(v.x); r[5] = (short)f2b(v.y);
  r[6] = (short)f2b(v.z); r[7] = (short)f2b(v.w);
  return r;
}
// async global->LDS DMA, 16B per lane, LDS dest = uniform base + lane*16
__device__ __forceinline__ void gl2lds(const unsigned short* g, unsigned short* l) {
  __builtin_amdgcn_global_load_lds(
      (const __attribute__((address_space(1))) unsigned int*)(g),
      (__attribute__((address_space(3))) unsigned int*)(l), 16, 0, 0);
}

// ---------------------------------------------------------------------------
// Weight pre-conversion fp32 -> bf16 (wkv, wq, wp, wout). 8 elems/thread.
__global__ __launch_bounds__(256, 2) void k_prep(
    const float* __restrict__ wkv, const float* __restrict__ wq,
    const float* __restrict__ wp, const float* __restrict__ wout,
    unsigned short* __restrict__ wkv_b, unsigned short* __restrict__ wq_b,
    unsigned short* __restrict__ wp_b, unsigned short* __restrict__ wout_b) {
  int id = blockIdx.x * 256 + threadIdx.x;  // 81920 total
  const float* src;
  unsigned short* dst;
  int off;
  if (id < 32768) { src = wkv; dst = wkv_b; off = id; }
  else if (id < 49152) { src = wq; dst = wq_b; off = id - 32768; }
  else if (id < 65536) { src = wp; dst = wp_b; off = id - 49152; }
  else { src = wout; dst = wout_b; off = id - 65536; }
  ((s16x8*)dst)[off] = ldf8(src + off * 8);
}

// ---------------------------------------------------------------------------
// Merged projection kernel. Blocks [0,512): KV projection over xm=cat(mem0,x)
// (block = ncgrp of 4, b, 128-j range; waves split j; A-fragments loaded once,
// reused for 4 weight chunks). Blocks [512,640): P projection (pe analytic).
__global__ __launch_bounds__(256, 2) void k_proj(
    const float* __restrict__ x, const float* __restrict__ mem,
    const unsigned short* __restrict__ wkv_b, const unsigned short* __restrict__ wp_b,
    unsigned short* __restrict__ Kk, unsigned short* __restrict__ Vt,
    unsigned short* __restrict__ Pp) {
  __shared__ float tbuf[4][16][128];
  const int lane = threadIdx.x & 63;
  const int w = threadIdx.x >> 6;
  const int l15 = lane & 15, l4 = lane >> 4;

  if (blockIdx.x < 512) {  // ---------------- KV projection ----------------
    const int ncg = (blockIdx.x & 3) * 4;
    const int b = (blockIdx.x >> 2) & 15;
    const int jb = (blockIdx.x >> 6) * 128 + w * 32;

    s16x8 A[2][4];
#pragma unroll
    for (int g = 0; g < 2; ++g) {
      int jr = jb + g * 16 + l15;
      const float* arow =
          (jr < 512 ? mem + (jr * 16 + b) * 128 : x + ((jr - 512) * 16 + b) * 128) + l4 * 8;
      A[g][0] = ldf8(arow); A[g][1] = ldf8(arow + 32);
      A[g][2] = ldf8(arow + 64); A[g][3] = ldf8(arow + 96);
    }

    for (int q = 0; q < 4; ++q) {
      const int nc = ncg + q;
      f32x4 acc[2][8] = {};
#pragma unroll
      for (int fc = 0; fc < 8; ++fc) {
        const unsigned short* brow = wkv_b + (nc * 128 + fc * 16 + l15) * 128 + l4 * 8;
        s16x8 b0 = ldg8(brow), b1 = ldg8(brow + 32), b2 = ldg8(brow + 64), b3 = ldg8(brow + 96);
#pragma unroll
        for (int g = 0; g < 2; ++g) {
          acc[g][fc] = MFMA(A[g][0], b0, acc[g][fc]);
          acc[g][fc] = MFMA(A[g][1], b1, acc[g][fc]);
          acc[g][fc] = MFMA(A[g][2], b2, acc[g][fc]);
          acc[g][fc] = MFMA(A[g][3], b3, acc[g][fc]);
        }
      }

      if (nc < 8) {  // K part, h = nc
#pragma unroll
        for (int g = 0; g < 2; ++g)
#pragma unroll
          for (int fc = 0; fc < 8; ++fc)
#pragma unroll
            for (int r = 0; r < 4; ++r) {
              int j = jb + g * 16 + l4 * 4 + r;
              Kk[((b * 8 + nc) * 1024 + j) * 128 + fc * 16 + l15] = f2b(acc[g][fc][r]);
            }
      } else {  // V part, h = nc-8: per-group LDS transpose (per-wave slice)
        const int h = nc - 8;
#pragma unroll
        for (int g = 0; g < 2; ++g) {
          LDS_FENCE();
#pragma unroll
          for (int fc = 0; fc < 8; ++fc)
#pragma unroll
            for (int r = 0; r < 4; ++r) tbuf[w][l4 * 4 + r][fc * 16 + l15] = acc[g][fc][r];
          LDS_FENCE();
#pragma unroll
          for (int half = 0; half < 2; ++half) {
            int dd = half * 64 + lane;
            unsigned int wd[8];
#pragma unroll
            for (int pw = 0; pw < 8; ++pw) {
              unsigned int lo = f2b(tbuf[w][2 * pw][dd]);
              unsigned int hi = f2b(tbuf[w][2 * pw + 1][dd]);
              wd[pw] = lo | (hi << 16);
            }
            unsigned short* dst = Vt + ((b * 8 + h) * 128 + dd) * 1024 + jb + g * 16;
            ((uint4*)dst)[0] = make_uint4(wd[0], wd[1], wd[2], wd[3]);
            ((uint4*)dst)[1] = make_uint4(wd[4], wd[5], wd[6], wd[7]);
          }
        }
      }
    }
  } else {  // ---------------- P projection ----------------
    const int pidx = blockIdx.x - 512;  // 0..127
    const int nc = pidx & 7;
    const int c0 = ((pidx >> 3) * 4 + w) * 16;

    const float pos = (float)(1023 - (c0 + l15));
    s16x8 a[4];
#pragma unroll
    for (int ks = 0; ks < 4; ++ks)
#pragma unroll
      for (int jj = 0; jj < 8; ++jj) {
        int e = ks * 32 + l4 * 8 + jj;
        int t = e & 63;
        float ang = pos * exp2f(-0.20762050593046014f * (float)t);  // 10000^(-t/64)
        float val = (e < 64) ? sinf(ang) : cosf(ang);
        a[ks][jj] = (short)f2b(val);
      }

    f32x4 acc[8] = {};
#pragma unroll
    for (int fc = 0; fc < 8; ++fc) {
      const unsigned short* brow = wp_b + (nc * 128 + fc * 16 + l15) * 128 + l4 * 8;
      acc[fc] = MFMA(a[0], ldg8(brow), acc[fc]);
      acc[fc] = MFMA(a[1], ldg8(brow + 32), acc[fc]);
      acc[fc] = MFMA(a[2], ldg8(brow + 64), acc[fc]);
      acc[fc] = MFMA(a[3], ldg8(brow + 96), acc[fc]);
    }
#pragma unroll
    for (int fc = 0; fc < 8; ++fc)
#pragma unroll
      for (int r = 0; r < 4; ++r)
        Pp[(nc * 1024 + c0 + l4 * 4 + r) * 128 + fc * 16 + l15] = f2b(acc[fc][r]);
  }
}

// ---------------------------------------------------------------------------
// Flash attention, block-cooperative FRAGMENT-ORDERED LDS staging (r12,
// verified PASS at 130.7 us). Each DMA instr fetches one MFMA B-fragment tile
// (lane=l4*16+l15 reads row l15, col ks*32+l4*8): 64B-contiguous per row ->
// 16x64B coalesced txns; compute reads are ds_read_b128 at base+lane*16.
// P-window circular (128 rows, advance 64/tile: 16KB P-DMA per tile).
__global__ __launch_bounds__(256, 2) void k_flash(
    const float* __restrict__ x, const unsigned short* __restrict__ wq_b,
    const unsigned short* __restrict__ Kk, const unsigned short* __restrict__ Vt,
    const unsigned short* __restrict__ Pp,
    const float* __restrict__ uu, const float* __restrict__ vv,
    unsigned short* __restrict__ OA) {
  __shared__ __align__(16) unsigned short L[37376];  // 73 KB
  unsigned short* LK = L;           // 16 frag-tiles x 512 (fc*4+ks)
  unsigned short* LV = L + 8192;    // 16 frag-tiles x 512 (fd*2+ks)
  unsigned short* LP = L + 16384;   // 32 frag-tiles x 512 (slot*4+ks), circular
  unsigned short* PB = L + 32768;   // probs: 4 waves x [16][72]

  const int lane = threadIdx.x & 63;
  const int w = threadIdx.x >> 6;
  const int bh = blockIdx.x & 127;
  const int igw = 7 - (blockIdx.x >> 7);  // longest blocks first
  const int iw = igw * 64 + w * 16;
  const int b = bh >> 3, h = bh & 7;
  const int l15 = lane & 15, l4 = lane >> 4;
  const int cb4 = 28 - igw * 4;  // P-window base row-chunk at t=0
  const float CSCALE = 0.08838834764831845f * 1.4426950408889634f;  // 1/sqrt(128)*log2e

  const unsigned short* K_b = Kk + bh * (1024 * 128);
  const unsigned short* V_b = Vt + bh * (128 * 1024);
  const unsigned short* P_h = Pp + h * (1024 * 128);

  // ---- fused Q projection (per-wave; LP used as scratch before staging)
  s16x8 qu[4], qv[4];
  {
    const float* arow = x + ((iw + l15) * 16 + b) * 128 + l4 * 8;
    s16x8 a0 = ldf8(arow), a1 = ldf8(arow + 32), a2 = ldf8(arow + 64), a3 = ldf8(arow + 96);
    f32x4 qd[8] = {};
#pragma unroll
    for (int fc = 0; fc < 8; ++fc) {
      const unsigned short* brow = wq_b + (h * 128 + fc * 16 + l15) * 128 + l4 * 8;
      qd[fc] = MFMA(a0, ldg8(brow), qd[fc]);
      qd[fc] = MFMA(a1, ldg8(brow + 32), qd[fc]);
      qd[fc] = MFMA(a2, ldg8(brow + 64), qd[fc]);
      qd[fc] = MFMA(a3, ldg8(brow + 96), qd[fc]);
    }
    unsigned short* qs = LP + w * 2176;  // [16][136] scratch per wave
#pragma unroll
    for (int fc = 0; fc < 8; ++fc) {
      float ud = uu[h * 128 + fc * 16 + l15];
#pragma unroll
      for (int r = 0; r < 4; ++r) qs[(l4 * 4 + r) * 136 + fc * 16 + l15] = f2b(qd[fc][r] + ud);
    }
    LDS_FENCE();
#pragma unroll
    for (int ks = 0; ks < 4; ++ks)
      qu[ks] = *(const s16x8*)&qs[l15 * 136 + ks * 32 + l4 * 8];
    LDS_FENCE();
#pragma unroll
    for (int fc = 0; fc < 8; ++fc) {
      float vd = vv[h * 128 + fc * 16 + l15];
#pragma unroll
      for (int r = 0; r < 4; ++r) qs[(l4 * 4 + r) * 136 + fc * 16 + l15] = f2b(qd[fc][r] + vd);
    }
    LDS_FENCE();
#pragma unroll
    for (int ks = 0; ks < 4; ++ks)
      qv[ks] = *(const s16x8*)&qs[l15 * 136 + ks * 32 + l4 * 8];
  }
  __syncthreads();  // LP scratch free before first DMA

  f32x4 O[8] = {};
  float rs[4] = {0.f, 0.f, 0.f, 0.f};

  const int tmax = igw + 9;  // j0 = t*64 covers j <= igw*64+63+512
  for (int t = 0; t < tmax; ++t) {
    const int j0 = t * 64;

    // ---- fragment-ordered cooperative DMA (this wave's share)
    // K: wave w stages fc=w, ks=q  (rows j0+w*16+l15, 64B/row contiguous)
#pragma unroll
    for (int q = 0; q < 4; ++q)
      gl2lds(K_b + (j0 + w * 16 + l15) * 128 + q * 32 + l4 * 8, LK + (w * 4 + q) * 512);
    // V: m = w*4+q -> fd=m>>1, ks=m&1 (rows fd*16+l15 of Vt, cols j0+ks*32+l4*8)
#pragma unroll
    for (int q = 0; q < 4; ++q) {
      int m = w * 4 + q, fd = m >> 1, ks = m & 1;
      gl2lds(V_b + (fd * 16 + l15) * 1024 + j0 + ks * 32 + l4 * 8, LV + m * 512);
    }
    // P: circular window. t=0: fill 8 row-chunks; t>0: advance 4 new chunks.
    if (t == 0) {
#pragma unroll
      for (int q = 0; q < 8; ++q) {
        int m = w * 8 + q, rc = m >> 2, ks = m & 3;
        int gchunk = cb4 + rc, slot = gchunk & 7;
        int grow = gchunk * 16 + l15;
        grow = (grow > 1023) ? 1023 : grow;  // clamped rows feed masked elems only
        gl2lds(P_h + grow * 128 + ks * 32 + l4 * 8, LP + (slot * 4 + ks) * 512);
      }
    } else {
#pragma unroll
      for (int q = 0; q < 4; ++q) {
        int m = w * 4 + q, gcq = m >> 2, ks = m & 3;
        int gchunk = cb4 + 4 * t + 4 + gcq, slot = gchunk & 7;
        int grow = gchunk * 16 + l15;
        grow = (grow > 1023) ? 1023 : grow;
        gl2lds(P_h + grow * 128 + ks * 32 + l4 * 8, LP + (slot * 4 + ks) * 512);
      }
    }
    __syncthreads();  // vmcnt drained at barrier -> all tiles staged

    // ---- QK^T from LDS (contiguous lane*16 reads)
    f32x4 sc[4];
#pragma unroll
    for (int fc = 0; fc < 4; ++fc) {
      f32x4 t4 = {};
#pragma unroll
      for (int ks = 0; ks < 4; ++ks)
        t4 = MFMA(qu[ks], *(const s16x8*)&LK[(fc * 4 + ks) * 512 + lane * 8], t4);
      sc[fc] = t4;
    }
    // ---- position band from circular LP window
    f32x4 sp[5];
#pragma unroll
    for (int pc = 0; pc < 5; ++pc) {
      f32x4 t4 = {};
      int slot = (cb4 + 4 * t + 3 - w + pc) & 7;
#pragma unroll
      for (int ks = 0; ks < 4; ++ks)
        t4 = MFMA(qv[ks], *(const s16x8*)&LP[(slot * 4 + ks) * 512 + lane * 8], t4);
      sp[pc] = t4;
    }

    // ---- combine + fixed-shift softmax, stage probs (per-wave buffer)
    unsigned short* pb = PB + w * 1152;
#pragma unroll
    for (int fc = 0; fc < 4; ++fc)
#pragma unroll
      for (int r = 0; r < 4; ++r) {
        int li = l4 * 4 + r;
        int jj = fc * 16 + l15;
        int cc = jj - li + 15;  // cc>>4 in {fc, fc+1}
        int src = (lane & 48) | (cc & 15);
        float g0 = __shfl(sp[fc][r], src, 64);
        float g1 = __shfl(sp[fc + 1][r], src, 64);
        float pv = ((cc >> 4) == fc) ? g0 : g1;
        float logit = (sc[fc][r] + pv) * CSCALE - 12.0f;  // fixed shift 2^-12
        if (j0 + jj > iw + li + 512) logit = -72.0f;      // masked
        float p = exp2f(logit);
        rs[r] += p;
        pb[li * 72 + jj] = f2b(p);
      }

    // ---- PV from LDS (probs same-wave write->read ordering, r3==r4 verified)
    s16x8 pa0 = *(const s16x8*)&pb[l15 * 72 + l4 * 8];
    s16x8 pa1 = *(const s16x8*)&pb[l15 * 72 + 32 + l4 * 8];
#pragma unroll
    for (int fd = 0; fd < 8; ++fd) {
      O[fd] = MFMA(pa0, *(const s16x8*)&LV[(fd * 2) * 512 + lane * 8], O[fd]);
      O[fd] = MFMA(pa1, *(const s16x8*)&LV[(fd * 2 + 1) * 512 + lane * 8], O[fd]);
    }
    __syncthreads();  // WAR: staged tiles consumed before next DMA
  }

  // one-time row-sum reduction
  float lrow[4];
#pragma unroll
  for (int r = 0; r < 4; ++r) {
    float s = rs[r];
#pragma unroll
    for (int off = 1; off < 16; off <<= 1) s += __shfl_xor(s, off, 64);
    lrow[r] = s;
  }
  // epilogue: O/l -> OA[i][b][h*128+d]
#pragma unroll
  for (int fd = 0; fd < 8; ++fd)
#pragma unroll
    for (int r = 0; r < 4; ++r) {
      int li = l4 * 4 + r;
      float o = O[fd][r] / lrow[r];
      OA[((iw + li) * 16 + b) * 1024 + h * 128 + fd * 16 + l15] = f2b(o);
    }
}

// ---------------------------------------------------------------------------
// Output projection: out[i][b][e] = sum_f OA[i][b][f] * wout[e][f], K=1024.
__global__ __launch_bounds__(256, 2) void k_out(
    const unsigned short* __restrict__ OA, const unsigned short* __restrict__ wout_b,
    const float* __restrict__ x, float* __restrict__ out) {
  const int lane = threadIdx.x & 63;
  const int w = threadIdx.x >> 6;
  const int half = blockIdx.x & 1;
  const int rt = (blockIdx.x >> 1) * 4 + w;
  const int l15 = lane & 15, l4 = lane >> 4;

  f32x4 acc[4] = {};
  const unsigned short* arow = OA + (rt * 16 + l15) * 1024 + l4 * 8;
#pragma unroll 4
  for (int ks = 0; ks < 32; ++ks) {
    s16x8 a = ldg8(arow + ks * 32);
#pragma unroll
    for (int fc = 0; fc < 4; ++fc) {
      const unsigned short* brow =
          wout_b + (half * 64 + fc * 16 + l15) * 1024 + ks * 32 + l4 * 8;
      acc[fc] = MFMA(a, ldg8(brow), acc[fc]);
    }
  }
#pragma unroll
  for (int fc = 0; fc < 4; ++fc)
#pragma unroll
    for (int r = 0; r < 4; ++r) {
      int rg = rt * 16 + l4 * 4 + r;
      int e = half * 64 + fc * 16 + l15;
      float v = acc[fc][r];
      out[rg * 128 + e] = v;
      out[2097152 + rg * 128 + e] = v;
    }
  // copy inputs (fp32) -> out1 (fp32, exact)
  const float4* src = (const float4*)(x + rt * 2048 + half * 1024);
  float4* dst = (float4*)(out + 1048576 + rt * 2048 + half * 1024);
  dst[lane] = src[lane];
  dst[64 + lane] = src[64 + lane];
  dst[128 + lane] = src[128 + lane];
  dst[192 + lane] = src[192 + lane];
}

// ---------------------------------------------------------------------------
extern "C" void kernel_launch(void* const* d_in, const int* in_sizes, int n_in,
                              void* d_out, int out_size, void* d_ws, size_t ws_size,
                              hipStream_t stream) {
  (void)in_sizes; (void)n_in; (void)out_size; (void)ws_size;
  const float* x    = (const float*)d_in[0];  // [512][16][128] fp32
  const float* mem  = (const float*)d_in[1];  // [2][512][16][128] fp32
  const float* wkv  = (const float*)d_in[2];  // [2048][128] fp32
  const float* wq   = (const float*)d_in[3];  // [1024][128] fp32
  const float* wp   = (const float*)d_in[4];  // [1024][128] fp32
  const float* wout = (const float*)d_in[5];  // [128][1024] fp32
  const float* uu   = (const float*)d_in[6];  // [8][128] fp32
  const float* vv   = (const float*)d_in[7];  // [8][128] fp32
  float* out = (float*)d_out;                 // fp32, 3,145,728 elems
  unsigned short* ws = (unsigned short*)d_ws;

  unsigned short* Kk     = ws;             // [16][8][1024][128] 16,777,216
  unsigned short* Vt     = ws + 16777216;  // [16][8][128][1024] 16,777,216
  unsigned short* Pp     = ws + 33554432;  // [8][1024][128]      1,048,576
  unsigned short* OA     = ws + 34603008;  // [512][16][1024]     8,388,608
  unsigned short* wkv_b  = ws + 42991616;  // 262,144
  unsigned short* wq_b   = ws + 43253760;  // 131,072
  unsigned short* wp_b   = ws + 43384832;  // 131,072
  unsigned short* wout_b = ws + 43515904;  // 131,072 -> end 43,646,976 (~83.3 MB)

  k_prep<<<320, 256, 0, stream>>>(wkv, wq, wp, wout, wkv_b, wq_b, wp_b, wout_b);
  k_proj<<<640, 256, 0, stream>>>(x, mem, wkv_b, wp_b, Kk, Vt, Pp);
  k_flash<<<1024, 256, 0, stream>>>(x, wq_b, Kk, Vt, Pp, uu, vv, OA);
  k_out<<<256, 256, 0, stream>>>(OA, wout_b, x, out);
}

// Round 16
// 264.693 us; speedup vs baseline: 1.4120x; 1.0461x over previous
//
#include <hip/hip_runtime.h>

// TemporalTX: T=512, B=16, D=128, H=8, DH=128, P=512, J=1024.
// INPUTS fp32; OUTPUT fp32. Workspace intermediates bf16.
// out = [layer_out (1M) | inputs copy (1M) | layer_out copy (1M)] fp32 elems.

typedef short s16x8 __attribute__((ext_vector_type(8)));
typedef float f32x4 __attribute__((ext_vector_type(4)));

#define MFMA(a, b, c) __builtin_amdgcn_mfma_f32_16x16x32_bf16((a), (b), (c), 0, 0, 0)
#define LDS_FENCE() asm volatile("s_waitcnt lgkmcnt(0)" ::: "memory")

__device__ __forceinline__ unsigned short f2b(float f) {
  unsigned int x = __builtin_bit_cast(unsigned int, f);
  x += 0x7fffu + ((x >> 16) & 1u);   // RNE
  return (unsigned short)(x >> 16);
}
__device__ __forceinline__ s16x8 ldg8(const unsigned short* p) {  // bf16 x8
  return *(const s16x8*)p;
}
__device__ __forceinline__ s16x8 ldf8(const float* p) {  // fp32 x8 -> bf16 x8
  float4 u = ((const float4*)p)[0];
  float4 v = ((const float4*)p)[1];
  s16x8 r;
  r[0] = (short)f2b(u.x); r[1] = (short)f2b(u.y);
  r[2] = (short)f2b(u.z); r[3] = (short)f2b(u.w);
  r[4] = (short)f2b(v.x); r[5] = (short)f2b(v.y);
  r[6] = (short)f2b(v.z); r[7] = (short)f2b(v.w);
  return r;
}
// async global->LDS DMA, 16B per lane, LDS dest = uniform base + lane*16
__device__ __forceinline__ void gl2lds(const unsigned short* g, unsigned short* l) {
  __builtin_amdgcn_global_load_lds(
      (const __attribute__((address_space(1))) unsigned int*)(g),
      (__attribute__((address_space(3))) unsigned int*)(l), 16, 0, 0);
}

// ---------------------------------------------------------------------------
// Weight pre-conversion fp32 -> bf16 (wkv, wq, wp, wout). 8 elems/thread.
__global__ __launch_bounds__(256, 2) void k_prep(
    const float* __restrict__ wkv, const float* __restrict__ wq,
    const float* __restrict__ wp, const float* __restrict__ wout,
    unsigned short* __restrict__ wkv_b, unsigned short* __restrict__ wq_b,
    unsigned short* __restrict__ wp_b, unsigned short* __restrict__ wout_b) {
  int id = blockIdx.x * 256 + threadIdx.x;  // 81920 total
  const float* src;
  unsigned short* dst;
  int off;
  if (id < 32768) { src = wkv; dst = wkv_b; off = id; }
  else if (id < 49152) { src = wq; dst = wq_b; off = id - 32768; }
  else if (id < 65536) { src = wp; dst = wp_b; off = id - 49152; }
  else { src = wout; dst = wout_b; off = id - 65536; }
  ((s16x8*)dst)[off] = ldf8(src + off * 8);
}

// ---------------------------------------------------------------------------
// Merged projection kernel. Blocks [0,512): KV projection over xm=cat(mem0,x)
// (block = ncgrp of 4, b, 128-j range; waves split j; A-fragments loaded once,
// reused for 4 weight chunks). Blocks [512,640): P projection (pe analytic).
__global__ __launch_bounds__(256, 2) void k_proj(
    const float* __restrict__ x, const float* __restrict__ mem,
    const unsigned short* __restrict__ wkv_b, const unsigned short* __restrict__ wp_b,
    unsigned short* __restrict__ Kk, unsigned short* __restrict__ Vt,
    unsigned short* __restrict__ Pp) {
  __shared__ float tbuf[4][16][128];
  const int lane = threadIdx.x & 63;
  const int w = threadIdx.x >> 6;
  const int l15 = lane & 15, l4 = lane >> 4;

  if (blockIdx.x < 512) {  // ---------------- KV projection ----------------
    const int ncg = (blockIdx.x & 3) * 4;
    const int b = (blockIdx.x >> 2) & 15;
    const int jb = (blockIdx.x >> 6) * 128 + w * 32;

    s16x8 A[2][4];
#pragma unroll
    for (int g = 0; g < 2; ++g) {
      int jr = jb + g * 16 + l15;
      const float* arow =
          (jr < 512 ? mem + (jr * 16 + b) * 128 : x + ((jr - 512) * 16 + b) * 128) + l4 * 8;
      A[g][0] = ldf8(arow); A[g][1] = ldf8(arow + 32);
      A[g][2] = ldf8(arow + 64); A[g][3] = ldf8(arow + 96);
    }

    for (int q = 0; q < 4; ++q) {
      const int nc = ncg + q;
      f32x4 acc[2][8] = {};
#pragma unroll
      for (int fc = 0; fc < 8; ++fc) {
        const unsigned short* brow = wkv_b + (nc * 128 + fc * 16 + l15) * 128 + l4 * 8;
        s16x8 b0 = ldg8(brow), b1 = ldg8(brow + 32), b2 = ldg8(brow + 64), b3 = ldg8(brow + 96);
#pragma unroll
        for (int g = 0; g < 2; ++g) {
          acc[g][fc] = MFMA(A[g][0], b0, acc[g][fc]);
          acc[g][fc] = MFMA(A[g][1], b1, acc[g][fc]);
          acc[g][fc] = MFMA(A[g][2], b2, acc[g][fc]);
          acc[g][fc] = MFMA(A[g][3], b3, acc[g][fc]);
        }
      }

      if (nc < 8) {  // K part, h = nc
#pragma unroll
        for (int g = 0; g < 2; ++g)
#pragma unroll
          for (int fc = 0; fc < 8; ++fc)
#pragma unroll
            for (int r = 0; r < 4; ++r) {
              int j = jb + g * 16 + l4 * 4 + r;
              Kk[((b * 8 + nc) * 1024 + j) * 128 + fc * 16 + l15] = f2b(acc[g][fc][r]);
            }
      } else {  // V part, h = nc-8: per-group LDS transpose (per-wave slice)
        const int h = nc - 8;
#pragma unroll
        for (int g = 0; g < 2; ++g) {
          LDS_FENCE();
#pragma unroll
          for (int fc = 0; fc < 8; ++fc)
#pragma unroll
            for (int r = 0; r < 4; ++r) tbuf[w][l4 * 4 + r][fc * 16 + l15] = acc[g][fc][r];
          LDS_FENCE();
#pragma unroll
          for (int half = 0; half < 2; ++half) {
            int dd = half * 64 + lane;
            unsigned int wd[8];
#pragma unroll
            for (int pw = 0; pw < 8; ++pw) {
              unsigned int lo = f2b(tbuf[w][2 * pw][dd]);
              unsigned int hi = f2b(tbuf[w][2 * pw + 1][dd]);
              wd[pw] = lo | (hi << 16);
            }
            unsigned short* dst = Vt + ((b * 8 + h) * 128 + dd) * 1024 + jb + g * 16;
            ((uint4*)dst)[0] = make_uint4(wd[0], wd[1], wd[2], wd[3]);
            ((uint4*)dst)[1] = make_uint4(wd[4], wd[5], wd[6], wd[7]);
          }
        }
      }
    }
  } else {  // ---------------- P projection ----------------
    const int pidx = blockIdx.x - 512;  // 0..127
    const int nc = pidx & 7;
    const int c0 = ((pidx >> 3) * 4 + w) * 16;

    const float pos = (float)(1023 - (c0 + l15));
    s16x8 a[4];
#pragma unroll
    for (int ks = 0; ks < 4; ++ks)
#pragma unroll
      for (int jj = 0; jj < 8; ++jj) {
        int e = ks * 32 + l4 * 8 + jj;
        int t = e & 63;
        float ang = pos * exp2f(-0.20762050593046014f * (float)t);  // 10000^(-t/64)
        float val = (e < 64) ? sinf(ang) : cosf(ang);
        a[ks][jj] = (short)f2b(val);
      }

    f32x4 acc[8] = {};
#pragma unroll
    for (int fc = 0; fc < 8; ++fc) {
      const unsigned short* brow = wp_b + (nc * 128 + fc * 16 + l15) * 128 + l4 * 8;
      acc[fc] = MFMA(a[0], ldg8(brow), acc[fc]);
      acc[fc] = MFMA(a[1], ldg8(brow + 32), acc[fc]);
      acc[fc] = MFMA(a[2], ldg8(brow + 64), acc[fc]);
      acc[fc] = MFMA(a[3], ldg8(brow + 96), acc[fc]);
    }
#pragma unroll
    for (int fc = 0; fc < 8; ++fc)
#pragma unroll
      for (int r = 0; r < 4; ++r)
        Pp[(nc * 1024 + c0 + l4 * 4 + r) * 128 + fc * 16 + l15] = f2b(acc[fc][r]);
  }
}

// ---------------------------------------------------------------------------
// Flash attention, fragment-ordered LDS staging + SOFTWARE-PIPELINED K-loop.
// Per tile: QK(t) | B_a (drains V(t),P(t)) | issue K(t+1) | band+softmax+PV(t)
// | B_b (drains K(t+1)) | issue V(t+1),P(t+1).  DMAs issued right after a
// barrier stay in flight until the next barrier -> overlap with compute.
// CSCALE folded into qu/qv; fixed softmax shift dropped (factors out).
__global__ __launch_bounds__(256, 2) void k_flash(
    const float* __restrict__ x, const unsigned short* __restrict__ wq_b,
    const unsigned short* __restrict__ Kk, const unsigned short* __restrict__ Vt,
    const unsigned short* __restrict__ Pp,
    const float* __restrict__ uu, const float* __restrict__ vv,
    unsigned short* __restrict__ OA) {
  __shared__ __align__(16) unsigned short L[37376];  // 73 KB
  unsigned short* LK = L;           // 16 frag-tiles x 512 (fc*4+ks)
  unsigned short* LV = L + 8192;    // 16 frag-tiles x 512 (fd*2+ks)
  unsigned short* LP = L + 16384;   // 32 frag-tiles x 512 (slot*4+ks), circular
  unsigned short* PB = L + 32768;   // probs: 4 waves x [16][72]

  const int lane = threadIdx.x & 63;
  const int w = threadIdx.x >> 6;
  const int bh = blockIdx.x & 127;
  const int igw = 7 - (blockIdx.x >> 7);  // longest blocks first
  const int iw = igw * 64 + w * 16;
  const int b = bh >> 3, h = bh & 7;
  const int l15 = lane & 15, l4 = lane >> 4;
  const int cb4 = 28 - igw * 4;  // P-window base row-chunk at t=0
  const float CSCALE = 0.08838834764831845f * 1.4426950408889634f;  // 1/sqrt(128)*log2e

  const unsigned short* K_b = Kk + bh * (1024 * 128);
  const unsigned short* V_b = Vt + bh * (128 * 1024);
  const unsigned short* P_h = Pp + h * (1024 * 128);
  const int tmax = igw + 9;  // j0 = t*64 covers j <= igw*64+63+512

  // ---- prefetch K(0), V(0) before Q-projection (overlap with its MFMAs)
#pragma unroll
  for (int q = 0; q < 4; ++q)
    gl2lds(K_b + (w * 16 + l15) * 128 + q * 32 + l4 * 8, LK + (w * 4 + q) * 512);
#pragma unroll
  for (int q = 0; q < 4; ++q) {
    int m = w * 4 + q, fd = m >> 1, ks = m & 1;
    gl2lds(V_b + (fd * 16 + l15) * 1024 + ks * 32 + l4 * 8, LV + m * 512);
  }

  // ---- fused Q projection (per-wave; LP used as scratch before staging)
  // CSCALE folded into qu/qv here: logits become sc+pv directly.
  s16x8 qu[4], qv[4];
  {
    const float* arow = x + ((iw + l15) * 16 + b) * 128 + l4 * 8;
    s16x8 a0 = ldf8(arow), a1 = ldf8(arow + 32), a2 = ldf8(arow + 64), a3 = ldf8(arow + 96);
    f32x4 qd[8] = {};
#pragma unroll
    for (int fc = 0; fc < 8; ++fc) {
      const unsigned short* brow = wq_b + (h * 128 + fc * 16 + l15) * 128 + l4 * 8;
      qd[fc] = MFMA(a0, ldg8(brow), qd[fc]);
      qd[fc] = MFMA(a1, ldg8(brow + 32), qd[fc]);
      qd[fc] = MFMA(a2, ldg8(brow + 64), qd[fc]);
      qd[fc] = MFMA(a3, ldg8(brow + 96), qd[fc]);
    }
    unsigned short* qs = LP + w * 2176;  // [16][136] scratch per wave
#pragma unroll
    for (int fc = 0; fc < 8; ++fc) {
      float ud = uu[h * 128 + fc * 16 + l15];
#pragma unroll
      for (int r = 0; r < 4; ++r)
        qs[(l4 * 4 + r) * 136 + fc * 16 + l15] = f2b((qd[fc][r] + ud) * CSCALE);
    }
    LDS_FENCE();
#pragma unroll
    for (int ks = 0; ks < 4; ++ks)
      qu[ks] = *(const s16x8*)&qs[l15 * 136 + ks * 32 + l4 * 8];
    LDS_FENCE();
#pragma unroll
    for (int fc = 0; fc < 8; ++fc) {
      float vd = vv[h * 128 + fc * 16 + l15];
#pragma unroll
      for (int r = 0; r < 4; ++r)
        qs[(l4 * 4 + r) * 136 + fc * 16 + l15] = f2b((qd[fc][r] + vd) * CSCALE);
    }
    LDS_FENCE();
#pragma unroll
    for (int ks = 0; ks < 4; ++ks)
      qv[ks] = *(const s16x8*)&qs[l15 * 136 + ks * 32 + l4 * 8];
  }
  __syncthreads();  // LP scratch free (drains K0/V0 too)

  // ---- prologue P window fill: chunks cb4..cb4+7 (tile-0 window)
#pragma unroll
  for (int q = 0; q < 8; ++q) {
    int m = w * 8 + q, rc = m >> 2, ks = m & 3;
    int gchunk = cb4 + rc, slot = gchunk & 7;
    int grow = gchunk * 16 + l15;
    grow = (grow > 1023) ? 1023 : grow;  // clamped rows feed masked elems only
    gl2lds(P_h + grow * 128 + ks * 32 + l4 * 8, LP + (slot * 4 + ks) * 512);
  }
  __syncthreads();  // P(0) staged

  f32x4 O[8] = {};
  float rs[4] = {0.f, 0.f, 0.f, 0.f};

  for (int t = 0; t < tmax; ++t) {
    const int j0 = t * 64;
    const int jp = (t + 1 < tmax) ? j0 + 64 : j0;  // prefetch j (block-uniform)

    // ---- QK^T from LK (K(t) staged; V(t),P(t) still in flight)
    f32x4 sc[4];
#pragma unroll
    for (int fc = 0; fc < 4; ++fc) {
      f32x4 t4 = {};
#pragma unroll
      for (int ks = 0; ks < 4; ++ks)
        t4 = MFMA(qu[ks], *(const s16x8*)&LK[(fc * 4 + ks) * 512 + lane * 8], t4);
      sc[fc] = t4;
    }

    __syncthreads();  // B_a: all waves done reading LK; drains V(t),P(t)

    // ---- issue K(t+1) -> LK (in flight through band/softmax/PV below)
#pragma unroll
    for (int q = 0; q < 4; ++q)
      gl2lds(K_b + (jp + w * 16 + l15) * 128 + q * 32 + l4 * 8, LK + (w * 4 + q) * 512);

    // ---- position band from circular LP window
    f32x4 sp[5];
#pragma unroll
    for (int pc = 0; pc < 5; ++pc) {
      f32x4 t4 = {};
      int slot = (cb4 + 4 * t + 3 - w + pc) & 7;
#pragma unroll
      for (int ks = 0; ks < 4; ++ks)
        t4 = MFMA(qv[ks], *(const s16x8*)&LP[(slot * 4 + ks) * 512 + lane * 8], t4);
      sp[pc] = t4;
    }

    // ---- combine + softmax (shift-free), stage probs (per-wave buffer)
    unsigned short* pb = PB + w * 1152;
#pragma unroll
    for (int fc = 0; fc < 4; ++fc)
#pragma unroll
      for (int r = 0; r < 4; ++r) {
        int li = l4 * 4 + r;
        int jj = fc * 16 + l15;
        int cc = jj - li + 15;  // cc>>4 in {fc, fc+1}
        int src = (lane & 48) | (cc & 15);
        float g0 = __shfl(sp[fc][r], src, 64);
        float g1 = __shfl(sp[fc + 1][r], src, 64);
        float pv = ((cc >> 4) == fc) ? g0 : g1;
        float logit = sc[fc][r] + pv;                 // pre-scaled by CSCALE
        if (j0 + jj > iw + li + 512) logit = -60.0f;  // masked (exp2 ~ 1e-18)
        float p = exp2f(logit);
        rs[r] += p;
        pb[li * 72 + jj] = f2b(p);
      }

    // ---- PV from LV (probs same-wave write->read ordering, r3==r4 verified)
    s16x8 pa0 = *(const s16x8*)&pb[l15 * 72 + l4 * 8];
    s16x8 pa1 = *(const s16x8*)&pb[l15 * 72 + 32 + l4 * 8];
#pragma unroll
    for (int fd = 0; fd < 8; ++fd) {
      O[fd] = MFMA(pa0, *(const s16x8*)&LV[(fd * 2) * 512 + lane * 8], O[fd]);
      O[fd] = MFMA(pa1, *(const s16x8*)&LV[(fd * 2 + 1) * 512 + lane * 8], O[fd]);
    }

    __syncthreads();  // B_b: done reading LP/LV; drains K(t+1)

    // ---- issue V(t+1) -> LV and P chunks (t+1 window) -> LP (circular)
#pragma unroll
    for (int q = 0; q < 4; ++q) {
      int m = w * 4 + q, fd = m >> 1, ks = m & 1;
      gl2lds(V_b + (fd * 16 + l15) * 1024 + jp + ks * 32 + l4 * 8, LV + m * 512);
    }
#pragma unroll
    for (int q = 0; q < 4; ++q) {
      int ks = q;  // wave w stages chunk cb4+4t+8+w, all 4 ks
      int gchunk = cb4 + 4 * t + 8 + w, slot = gchunk & 7;
      int grow = gchunk * 16 + l15;
      grow = (grow > 1023) ? 1023 : grow;
      gl2lds(P_h + grow * 128 + ks * 32 + l4 * 8, LP + (slot * 4 + ks) * 512);
    }
  }

  // one-time row-sum reduction
  float lrow[4];
#pragma unroll
  for (int r = 0; r < 4; ++r) {
    float s = rs[r];
#pragma unroll
    for (int off = 1; off < 16; off <<= 1) s += __shfl_xor(s, off, 64);
    lrow[r] = s;
  }
  // epilogue: O/l -> OA[i][b][h*128+d]
#pragma unroll
  for (int fd = 0; fd < 8; ++fd)
#pragma unroll
    for (int r = 0; r < 4; ++r) {
      int li = l4 * 4 + r;
      float o = O[fd][r] / lrow[r];
      OA[((iw + li) * 16 + b) * 1024 + h * 128 + fd * 16 + l15] = f2b(o);
    }
}

// ---------------------------------------------------------------------------
// Output projection: out[i][b][e] = sum_f OA[i][b][f] * wout[e][f], K=1024.
__global__ __launch_bounds__(256, 2) void k_out(
    const unsigned short* __restrict__ OA, const unsigned short* __restrict__ wout_b,
    const float* __restrict__ x, float* __restrict__ out) {
  const int lane = threadIdx.x & 63;
  const int w = threadIdx.x >> 6;
  const int half = blockIdx.x & 1;
  const int rt = (blockIdx.x >> 1) * 4 + w;
  const int l15 = lane & 15, l4 = lane >> 4;

  f32x4 acc[4] = {};
  const unsigned short* arow = OA + (rt * 16 + l15) * 1024 + l4 * 8;
#pragma unroll 4
  for (int ks = 0; ks < 32; ++ks) {
    s16x8 a = ldg8(arow + ks * 32);
#pragma unroll
    for (int fc = 0; fc < 4; ++fc) {
      const unsigned short* brow =
          wout_b + (half * 64 + fc * 16 + l15) * 1024 + ks * 32 + l4 * 8;
      acc[fc] = MFMA(a, ldg8(brow), acc[fc]);
    }
  }
#pragma unroll
  for (int fc = 0; fc < 4; ++fc)
#pragma unroll
    for (int r = 0; r < 4; ++r) {
      int rg = rt * 16 + l4 * 4 + r;
      int e = half * 64 + fc * 16 + l15;
      float v = acc[fc][r];
      out[rg * 128 + e] = v;
      out[2097152 + rg * 128 + e] = v;
    }
  // copy inputs (fp32) -> out1 (fp32, exact)
  const float4* src = (const float4*)(x + rt * 2048 + half * 1024);
  float4* dst = (float4*)(out + 1048576 + rt * 2048 + half * 1024);
  dst[lane] = src[lane];
  dst[64 + lane] = src[64 + lane];
  dst[128 + lane] = src[128 + lane];
  dst[192 + lane] = src[192 + lane];
}

// ---------------------------------------------------------------------------
extern "C" void kernel_launch(void* const* d_in, const int* in_sizes, int n_in,
                              void* d_out, int out_size, void* d_ws, size_t ws_size,
                              hipStream_t stream) {
  (void)in_sizes; (void)n_in; (void)out_size; (void)ws_size;
  const float* x    = (const float*)d_in[0];  // [512][16][128] fp32
  const float* mem  = (const float*)d_in[1];  // [2][512][16][128] fp32
  const float* wkv  = (const float*)d_in[2];  // [2048][128] fp32
  const float* wq   = (const float*)d_in[3];  // [1024][128] fp32
  const float* wp   = (const float*)d_in[4];  // [1024][128] fp32
  const float* wout = (const float*)d_in[5];  // [128][1024] fp32
  const float* uu   = (const float*)d_in[6];  // [8][128] fp32
  const float* vv   = (const float*)d_in[7];  // [8][128] fp32
  float* out = (float*)d_out;                 // fp32, 3,145,728 elems
  unsigned short* ws = (unsigned short*)d_ws;

  unsigned short* Kk     = ws;             // [16][8][1024][128] 16,777,216
  unsigned short* Vt     = ws + 16777216;  // [16][8][128][1024] 16,777,216
  unsigned short* Pp     = ws + 33554432;  // [8][1024][128]      1,048,576
  unsigned short* OA     = ws + 34603008;  // [512][16][1024]     8,388,608
  unsigned short* wkv_b  = ws + 42991616;  // 262,144
  unsigned short* wq_b   = ws + 43253760;  // 131,072
  unsigned short* wp_b   = ws + 43384832;  // 131,072
  unsigned short* wout_b = ws + 43515904;  // 131,072 -> end 43,646,976 (~83.3 MB)

  k_prep<<<320, 256, 0, stream>>>(wkv, wq, wp, wout, wkv_b, wq_b, wp_b, wout_b);
  k_proj<<<640, 256, 0, stream>>>(x, mem, wkv_b, wp_b, Kk, Vt, Pp);
  k_flash<<<1024, 256, 0, stream>>>(x, wq_b, Kk, Vt, Pp, uu, vv, OA);
  k_out<<<256, 256, 0, stream>>>(OA, wout_b, x, out);
}

// Round 17
// 259.040 us; speedup vs baseline: 1.4428x; 1.0218x over previous
//
#include <hip/hip_runtime.h>

// TemporalTX: T=512, B=16, D=128, H=8, DH=128, P=512, J=1024.
// INPUTS fp32; OUTPUT fp32. Workspace intermediates bf16.
// out = [layer_out (1M) | inputs copy (1M) | layer_out copy (1M)] fp32 elems.

typedef short s16x8 __attribute__((ext_vector_type(8)));
typedef float f32x4 __attribute__((ext_vector_type(4)));

#define MFMA(a, b, c) __builtin_amdgcn_mfma_f32_16x16x32_bf16((a), (b), (c), 0, 0, 0)
#define LDS_FENCE() asm volatile("s_waitcnt lgkmcnt(0)" ::: "memory")

__device__ __forceinline__ unsigned short f2b(float f) {
  unsigned int x = __builtin_bit_cast(unsigned int, f);
  x += 0x7fffu + ((x >> 16) & 1u);   // RNE
  return (unsigned short)(x >> 16);
}
__device__ __forceinline__ s16x8 ldg8(const unsigned short* p) {  // bf16 x8
  return *(const s16x8*)p;
}
__device__ __forceinline__ s16x8 ldf8(const float* p) {  // fp32 x8 -> bf16 x8
  float4 u = ((const float4*)p)[0];
  float4 v = ((const float4*)p)[1];
  s16x8 r;
  r[0] = (short)f2b(u.x); r[1] = (short)f2b(u.y);
  r[2] = (short)f2b(u.z); r[3] = (short)f2b(u.w);
  r[4] = (short)f2b(v.x); r[5] = (short)f2b(v.y);
  r[6] = (short)f2b(v.z); r[7] = (short)f2b(v.w);
  return r;
}
// async global->LDS DMA, 16B per lane, LDS dest = uniform base + lane*16
__device__ __forceinline__ void gl2lds(const unsigned short* g, unsigned short* l) {
  __builtin_amdgcn_global_load_lds(
      (const __attribute__((address_space(1))) unsigned int*)(g),
      (__attribute__((address_space(3))) unsigned int*)(l), 16, 0, 0);
}

// ---------------------------------------------------------------------------
// Weight pre-conversion fp32 -> bf16 (wkv, wq, wp, wout). 8 elems/thread.
__global__ __launch_bounds__(256, 2) void k_prep(
    const float* __restrict__ wkv, const float* __restrict__ wq,
    const float* __restrict__ wp, const float* __restrict__ wout,
    unsigned short* __restrict__ wkv_b, unsigned short* __restrict__ wq_b,
    unsigned short* __restrict__ wp_b, unsigned short* __restrict__ wout_b) {
  int id = blockIdx.x * 256 + threadIdx.x;  // 81920 total
  const float* src;
  unsigned short* dst;
  int off;
  if (id < 32768) { src = wkv; dst = wkv_b; off = id; }
  else if (id < 49152) { src = wq; dst = wq_b; off = id - 32768; }
  else if (id < 65536) { src = wp; dst = wp_b; off = id - 49152; }
  else { src = wout; dst = wout_b; off = id - 65536; }
  ((s16x8*)dst)[off] = ldf8(src + off * 8);
}

// ---------------------------------------------------------------------------
// Merged projection kernel. Blocks [0,1024): KV projection over xm=cat(mem0,x)
// (block = ncgrp of 2, b, 128-j range; waves split j; A-fragments loaded once,
// reused for 2 weight chunks). Blocks [1024,1152): P projection (pe analytic).
__global__ __launch_bounds__(256, 2) void k_proj(
    const float* __restrict__ x, const float* __restrict__ mem,
    const unsigned short* __restrict__ wkv_b, const unsigned short* __restrict__ wp_b,
    unsigned short* __restrict__ Kk, unsigned short* __restrict__ Vt,
    unsigned short* __restrict__ Pp) {
  __shared__ float tbuf[4][16][128];
  const int lane = threadIdx.x & 63;
  const int w = threadIdx.x >> 6;
  const int l15 = lane & 15, l4 = lane >> 4;

  if (blockIdx.x < 1024) {  // ---------------- KV projection ----------------
    const int ncg = (blockIdx.x & 7) * 2;            // 0,2,...,14
    const int b = (blockIdx.x >> 3) & 15;
    const int jb = (blockIdx.x >> 7) * 128 + w * 32;

    s16x8 A[2][4];
#pragma unroll
    for (int g = 0; g < 2; ++g) {
      int jr = jb + g * 16 + l15;
      const float* arow =
          (jr < 512 ? mem + (jr * 16 + b) * 128 : x + ((jr - 512) * 16 + b) * 128) + l4 * 8;
      A[g][0] = ldf8(arow); A[g][1] = ldf8(arow + 32);
      A[g][2] = ldf8(arow + 64); A[g][3] = ldf8(arow + 96);
    }

    for (int q = 0; q < 2; ++q) {
      const int nc = ncg + q;
      f32x4 acc[2][8] = {};
#pragma unroll
      for (int fc = 0; fc < 8; ++fc) {
        const unsigned short* brow = wkv_b + (nc * 128 + fc * 16 + l15) * 128 + l4 * 8;
        s16x8 b0 = ldg8(brow), b1 = ldg8(brow + 32), b2 = ldg8(brow + 64), b3 = ldg8(brow + 96);
#pragma unroll
        for (int g = 0; g < 2; ++g) {
          acc[g][fc] = MFMA(A[g][0], b0, acc[g][fc]);
          acc[g][fc] = MFMA(A[g][1], b1, acc[g][fc]);
          acc[g][fc] = MFMA(A[g][2], b2, acc[g][fc]);
          acc[g][fc] = MFMA(A[g][3], b3, acc[g][fc]);
        }
      }

      if (nc < 8) {  // K part, h = nc
#pragma unroll
        for (int g = 0; g < 2; ++g)
#pragma unroll
          for (int fc = 0; fc < 8; ++fc)
#pragma unroll
            for (int r = 0; r < 4; ++r) {
              int j = jb + g * 16 + l4 * 4 + r;
              Kk[((b * 8 + nc) * 1024 + j) * 128 + fc * 16 + l15] = f2b(acc[g][fc][r]);
            }
      } else {  // V part, h = nc-8: per-group LDS transpose (per-wave slice)
        const int h = nc - 8;
#pragma unroll
        for (int g = 0; g < 2; ++g) {
          LDS_FENCE();
#pragma unroll
          for (int fc = 0; fc < 8; ++fc)
#pragma unroll
            for (int r = 0; r < 4; ++r) tbuf[w][l4 * 4 + r][fc * 16 + l15] = acc[g][fc][r];
          LDS_FENCE();
#pragma unroll
          for (int half = 0; half < 2; ++half) {
            int dd = half * 64 + lane;
            unsigned int wd[8];
#pragma unroll
            for (int pw = 0; pw < 8; ++pw) {
              unsigned int lo = f2b(tbuf[w][2 * pw][dd]);
              unsigned int hi = f2b(tbuf[w][2 * pw + 1][dd]);
              wd[pw] = lo | (hi << 16);
            }
            unsigned short* dst = Vt + ((b * 8 + h) * 128 + dd) * 1024 + jb + g * 16;
            ((uint4*)dst)[0] = make_uint4(wd[0], wd[1], wd[2], wd[3]);
            ((uint4*)dst)[1] = make_uint4(wd[4], wd[5], wd[6], wd[7]);
          }
        }
      }
    }
  } else {  // ---------------- P projection ----------------
    const int pidx = blockIdx.x - 1024;  // 0..127
    const int nc = pidx & 7;
    const int c0 = ((pidx >> 3) * 4 + w) * 16;

    const float pos = (float)(1023 - (c0 + l15));
    s16x8 a[4];
#pragma unroll
    for (int ks = 0; ks < 4; ++ks)
#pragma unroll
      for (int jj = 0; jj < 8; ++jj) {
        int e = ks * 32 + l4 * 8 + jj;
        int t = e & 63;
        float ang = pos * exp2f(-0.20762050593046014f * (float)t);  // 10000^(-t/64)
        float val = (e < 64) ? sinf(ang) : cosf(ang);
        a[ks][jj] = (short)f2b(val);
      }

    f32x4 acc[8] = {};
#pragma unroll
    for (int fc = 0; fc < 8; ++fc) {
      const unsigned short* brow = wp_b + (nc * 128 + fc * 16 + l15) * 128 + l4 * 8;
      acc[fc] = MFMA(a[0], ldg8(brow), acc[fc]);
      acc[fc] = MFMA(a[1], ldg8(brow + 32), acc[fc]);
      acc[fc] = MFMA(a[2], ldg8(brow + 64), acc[fc]);
      acc[fc] = MFMA(a[3], ldg8(brow + 96), acc[fc]);
    }
#pragma unroll
    for (int fc = 0; fc < 8; ++fc)
#pragma unroll
      for (int r = 0; r < 4; ++r)
        Pp[(nc * 1024 + c0 + l4 * 4 + r) * 128 + fc * 16 + l15] = f2b(acc[fc][r]);
  }
}

// ---------------------------------------------------------------------------
// Flash attention, fragment-ordered LDS staging + SOFTWARE-PIPELINED K-loop
// (r16-verified at 119 us). Per tile: QK(t) | B_a (drains V(t),P(t)) |
// issue K(t+1) | band+softmax+PV(t) | B_b (drains K(t+1)) | issue V(t+1),P(t+1).
// CSCALE folded into qu/qv; shift-free softmax.
__global__ __launch_bounds__(256, 2) void k_flash(
    const float* __restrict__ x, const unsigned short* __restrict__ wq_b,
    const unsigned short* __restrict__ Kk, const unsigned short* __restrict__ Vt,
    const unsigned short* __restrict__ Pp,
    const float* __restrict__ uu, const float* __restrict__ vv,
    unsigned short* __restrict__ OA) {
  __shared__ __align__(16) unsigned short L[37376];  // 73 KB
  unsigned short* LK = L;           // 16 frag-tiles x 512 (fc*4+ks)
  unsigned short* LV = L + 8192;    // 16 frag-tiles x 512 (fd*2+ks)
  unsigned short* LP = L + 16384;   // 32 frag-tiles x 512 (slot*4+ks), circular
  unsigned short* PB = L + 32768;   // probs: 4 waves x [16][72]

  const int lane = threadIdx.x & 63;
  const int w = threadIdx.x >> 6;
  const int bh = blockIdx.x & 127;
  const int igw = 7 - (blockIdx.x >> 7);  // longest blocks first
  const int iw = igw * 64 + w * 16;
  const int b = bh >> 3, h = bh & 7;
  const int l15 = lane & 15, l4 = lane >> 4;
  const int cb4 = 28 - igw * 4;  // P-window base row-chunk at t=0
  const float CSCALE = 0.08838834764831845f * 1.4426950408889634f;  // 1/sqrt(128)*log2e

  const unsigned short* K_b = Kk + bh * (1024 * 128);
  const unsigned short* V_b = Vt + bh * (128 * 1024);
  const unsigned short* P_h = Pp + h * (1024 * 128);
  const int tmax = igw + 9;  // j0 = t*64 covers j <= igw*64+63+512

  // ---- prefetch K(0), V(0) before Q-projection (overlap with its MFMAs)
#pragma unroll
  for (int q = 0; q < 4; ++q)
    gl2lds(K_b + (w * 16 + l15) * 128 + q * 32 + l4 * 8, LK + (w * 4 + q) * 512);
#pragma unroll
  for (int q = 0; q < 4; ++q) {
    int m = w * 4 + q, fd = m >> 1, ks = m & 1;
    gl2lds(V_b + (fd * 16 + l15) * 1024 + ks * 32 + l4 * 8, LV + m * 512);
  }

  // ---- fused Q projection (per-wave; LP used as scratch before staging)
  s16x8 qu[4], qv[4];
  {
    const float* arow = x + ((iw + l15) * 16 + b) * 128 + l4 * 8;
    s16x8 a0 = ldf8(arow), a1 = ldf8(arow + 32), a2 = ldf8(arow + 64), a3 = ldf8(arow + 96);
    f32x4 qd[8] = {};
#pragma unroll
    for (int fc = 0; fc < 8; ++fc) {
      const unsigned short* brow = wq_b + (h * 128 + fc * 16 + l15) * 128 + l4 * 8;
      qd[fc] = MFMA(a0, ldg8(brow), qd[fc]);
      qd[fc] = MFMA(a1, ldg8(brow + 32), qd[fc]);
      qd[fc] = MFMA(a2, ldg8(brow + 64), qd[fc]);
      qd[fc] = MFMA(a3, ldg8(brow + 96), qd[fc]);
    }
    unsigned short* qs = LP + w * 2176;  // [16][136] scratch per wave
#pragma unroll
    for (int fc = 0; fc < 8; ++fc) {
      float ud = uu[h * 128 + fc * 16 + l15];
#pragma unroll
      for (int r = 0; r < 4; ++r)
        qs[(l4 * 4 + r) * 136 + fc * 16 + l15] = f2b((qd[fc][r] + ud) * CSCALE);
    }
    LDS_FENCE();
#pragma unroll
    for (int ks = 0; ks < 4; ++ks)
      qu[ks] = *(const s16x8*)&qs[l15 * 136 + ks * 32 + l4 * 8];
    LDS_FENCE();
#pragma unroll
    for (int fc = 0; fc < 8; ++fc) {
      float vd = vv[h * 128 + fc * 16 + l15];
#pragma unroll
      for (int r = 0; r < 4; ++r)
        qs[(l4 * 4 + r) * 136 + fc * 16 + l15] = f2b((qd[fc][r] + vd) * CSCALE);
    }
    LDS_FENCE();
#pragma unroll
    for (int ks = 0; ks < 4; ++ks)
      qv[ks] = *(const s16x8*)&qs[l15 * 136 + ks * 32 + l4 * 8];
  }
  __syncthreads();  // LP scratch free (drains K0/V0 too)

  // ---- prologue P window fill: chunks cb4..cb4+7 (tile-0 window)
#pragma unroll
  for (int q = 0; q < 8; ++q) {
    int m = w * 8 + q, rc = m >> 2, ks = m & 3;
    int gchunk = cb4 + rc, slot = gchunk & 7;
    int grow = gchunk * 16 + l15;
    grow = (grow > 1023) ? 1023 : grow;  // clamped rows feed masked elems only
    gl2lds(P_h + grow * 128 + ks * 32 + l4 * 8, LP + (slot * 4 + ks) * 512);
  }
  __syncthreads();  // P(0) staged

  f32x4 O[8] = {};
  float rs[4] = {0.f, 0.f, 0.f, 0.f};

  for (int t = 0; t < tmax; ++t) {
    const int j0 = t * 64;
    const int jp = (t + 1 < tmax) ? j0 + 64 : j0;  // prefetch j (block-uniform)

    // ---- QK^T from LK (K(t) staged; V(t),P(t) still in flight)
    f32x4 sc[4];
#pragma unroll
    for (int fc = 0; fc < 4; ++fc) {
      f32x4 t4 = {};
#pragma unroll
      for (int ks = 0; ks < 4; ++ks)
        t4 = MFMA(qu[ks], *(const s16x8*)&LK[(fc * 4 + ks) * 512 + lane * 8], t4);
      sc[fc] = t4;
    }

    __syncthreads();  // B_a: all waves done reading LK; drains V(t),P(t)

    // ---- issue K(t+1) -> LK (in flight through band/softmax/PV below)
#pragma unroll
    for (int q = 0; q < 4; ++q)
      gl2lds(K_b + (jp + w * 16 + l15) * 128 + q * 32 + l4 * 8, LK + (w * 4 + q) * 512);

    // ---- position band from circular LP window
    f32x4 sp[5];
#pragma unroll
    for (int pc = 0; pc < 5; ++pc) {
      f32x4 t4 = {};
      int slot = (cb4 + 4 * t + 3 - w + pc) & 7;
#pragma unroll
      for (int ks = 0; ks < 4; ++ks)
        t4 = MFMA(qv[ks], *(const s16x8*)&LP[(slot * 4 + ks) * 512 + lane * 8], t4);
      sp[pc] = t4;
    }

    // ---- combine + softmax (shift-free), stage probs (per-wave buffer)
    unsigned short* pb = PB + w * 1152;
#pragma unroll
    for (int fc = 0; fc < 4; ++fc)
#pragma unroll
      for (int r = 0; r < 4; ++r) {
        int li = l4 * 4 + r;
        int jj = fc * 16 + l15;
        int cc = jj - li + 15;  // cc>>4 in {fc, fc+1}
        int src = (lane & 48) | (cc & 15);
        float g0 = __shfl(sp[fc][r], src, 64);
        float g1 = __shfl(sp[fc + 1][r], src, 64);
        float pv = ((cc >> 4) == fc) ? g0 : g1;
        float logit = sc[fc][r] + pv;                 // pre-scaled by CSCALE
        if (j0 + jj > iw + li + 512) logit = -60.0f;  // masked (exp2 ~ 1e-18)
        float p = exp2f(logit);
        rs[r] += p;
        pb[li * 72 + jj] = f2b(p);
      }

    // ---- PV from LV (probs same-wave write->read ordering, r3==r4 verified)
    s16x8 pa0 = *(const s16x8*)&pb[l15 * 72 + l4 * 8];
    s16x8 pa1 = *(const s16x8*)&pb[l15 * 72 + 32 + l4 * 8];
#pragma unroll
    for (int fd = 0; fd < 8; ++fd) {
      O[fd] = MFMA(pa0, *(const s16x8*)&LV[(fd * 2) * 512 + lane * 8], O[fd]);
      O[fd] = MFMA(pa1, *(const s16x8*)&LV[(fd * 2 + 1) * 512 + lane * 8], O[fd]);
    }

    __syncthreads();  // B_b: done reading LP/LV; drains K(t+1)

    // ---- issue V(t+1) -> LV and P chunks (t+1 window) -> LP (circular)
#pragma unroll
    for (int q = 0; q < 4; ++q) {
      int m = w * 4 + q, fd = m >> 1, ks = m & 1;
      gl2lds(V_b + (fd * 16 + l15) * 1024 + jp + ks * 32 + l4 * 8, LV + m * 512);
    }
#pragma unroll
    for (int q = 0; q < 4; ++q) {
      int ks = q;  // wave w stages chunk cb4+4t+8+w, all 4 ks
      int gchunk = cb4 + 4 * t + 8 + w, slot = gchunk & 7;
      int grow = gchunk * 16 + l15;
      grow = (grow > 1023) ? 1023 : grow;
      gl2lds(P_h + grow * 128 + ks * 32 + l4 * 8, LP + (slot * 4 + ks) * 512);
    }
  }

  // one-time row-sum reduction
  float lrow[4];
#pragma unroll
  for (int r = 0; r < 4; ++r) {
    float s = rs[r];
#pragma unroll
    for (int off = 1; off < 16; off <<= 1) s += __shfl_xor(s, off, 64);
    lrow[r] = s;
  }
  // epilogue: O/l -> OA[i][b][h*128+d]
#pragma unroll
  for (int fd = 0; fd < 8; ++fd)
#pragma unroll
    for (int r = 0; r < 4; ++r) {
      int li = l4 * 4 + r;
      float o = O[fd][r] / lrow[r];
      OA[((iw + li) * 16 + b) * 1024 + h * 128 + fd * 16 + l15] = f2b(o);
    }
}

// ---------------------------------------------------------------------------
// Output projection: out[i][b][e] = sum_f OA[i][b][f] * wout[e][f], K=1024.
// Grid 512: block = (e-quarter of 32, rt-group of 4). 2 blocks/CU.
__global__ __launch_bounds__(256, 2) void k_out(
    const unsigned short* __restrict__ OA, const unsigned short* __restrict__ wout_b,
    const float* __restrict__ x, float* __restrict__ out) {
  const int lane = threadIdx.x & 63;
  const int w = threadIdx.x >> 6;
  const int qtr = blockIdx.x & 3;             // e in [qtr*32, qtr*32+32)
  const int rt = (blockIdx.x >> 2) * 4 + w;   // i-tile 0..511
  const int l15 = lane & 15, l4 = lane >> 4;

  f32x4 acc[2] = {};
  const unsigned short* arow = OA + (rt * 16 + l15) * 1024 + l4 * 8;
#pragma unroll 4
  for (int ks = 0; ks < 32; ++ks) {
    s16x8 a = ldg8(arow + ks * 32);
#pragma unroll
    for (int fc = 0; fc < 2; ++fc) {
      const unsigned short* brow =
          wout_b + (qtr * 32 + fc * 16 + l15) * 1024 + ks * 32 + l4 * 8;
      acc[fc] = MFMA(a, ldg8(brow), acc[fc]);
    }
  }
#pragma unroll
  for (int fc = 0; fc < 2; ++fc)
#pragma unroll
    for (int r = 0; r < 4; ++r) {
      int rg = rt * 16 + l4 * 4 + r;
      int e = qtr * 32 + fc * 16 + l15;
      float v = acc[fc][r];
      out[rg * 128 + e] = v;
      out[2097152 + rg * 128 + e] = v;
    }
  // copy inputs (fp32) -> out1 (fp32, exact): 512 floats per wave-slot
  const int gid = blockIdx.x * 4 + w;  // 0..2047
  const float4* src = (const float4*)(x + gid * 512);
  float4* dst = (float4*)(out + 1048576 + gid * 512);
  dst[lane] = src[lane];
  dst[64 + lane] = src[64 + lane];
}

// ---------------------------------------------------------------------------
extern "C" void kernel_launch(void* const* d_in, const int* in_sizes, int n_in,
                              void* d_out, int out_size, void* d_ws, size_t ws_size,
                              hipStream_t stream) {
  (void)in_sizes; (void)n_in; (void)out_size; (void)ws_size;
  const float* x    = (const float*)d_in[0];  // [512][16][128] fp32
  const float* mem  = (const float*)d_in[1];  // [2][512][16][128] fp32
  const float* wkv  = (const float*)d_in[2];  // [2048][128] fp32
  const float* wq   = (const float*)d_in[3];  // [1024][128] fp32
  const float* wp   = (const float*)d_in[4];  // [1024][128] fp32
  const float* wout = (const float*)d_in[5];  // [128][1024] fp32
  const float* uu   = (const float*)d_in[6];  // [8][128] fp32
  const float* vv   = (const float*)d_in[7];  // [8][128] fp32
  float* out = (float*)d_out;                 // fp32, 3,145,728 elems
  unsigned short* ws = (unsigned short*)d_ws;

  unsigned short* Kk     = ws;             // [16][8][1024][128] 16,777,216
  unsigned short* Vt     = ws + 16777216;  // [16][8][128][1024] 16,777,216
  unsigned short* Pp     = ws + 33554432;  // [8][1024][128]      1,048,576
  unsigned short* OA     = ws + 34603008;  // [512][16][1024]     8,388,608
  unsigned short* wkv_b  = ws + 42991616;  // 262,144
  unsigned short* wq_b   = ws + 43253760;  // 131,072
  unsigned short* wp_b   = ws + 43384832;  // 131,072
  unsigned short* wout_b = ws + 43515904;  // 131,072 -> end 43,646,976 (~83.3 MB)

  k_prep<<<320, 256, 0, stream>>>(wkv, wq, wp, wout, wkv_b, wq_b, wp_b, wout_b);
  k_proj<<<1152, 256, 0, stream>>>(x, mem, wkv_b, wp_b, Kk, Vt, Pp);
  k_flash<<<1024, 256, 0, stream>>>(x, wq_b, Kk, Vt, Pp, uu, vv, OA);
  k_out<<<512, 256, 0, stream>>>(OA, wout_b, x, out);
}